// Round 12
// baseline (245.530 us; speedup 1.0000x reference)
//
#include <hip/hip_runtime.h>
#include <hip/hip_fp16.h>

// ---------------------------------------------------------------------------
// GCN 3-layer forward on MI355X.  (r12: 4-wave GEMM blocks for 3 waves/SIMD)
// init+splitW(fused) -> deg -> scan1(+dinv) -> scan23 -> fill(countdown)
//   -> [MFMA GEMM (bf16x3, LDS-staged A) -> AGG] x3          (11 launches)
// GEMM: 64-row x F blocks, 256 thr = 4 waves (2 row-halves x 2 col-halves),
//       wave tile 32x64 (F=128) / 32x32 (F=64). Grid 782 -> 12 waves/CU =
//       3 waves/SIMD (r11 had 2-wave blocks -> 1.5/SIMD: the barrier drain
//       had nothing to hide under). A K-tile [64][32] f32 double-buffered in
//       LDS via global_load_lds (src chunk-swizzle c^=(row&7), linear dest);
//       B direct global (L2-resident W splits), issued before the stage DMA.
// AGG:  per-dst gather of fp16 H' rows; F=128 wave/node, F=64 half-wave/node.
//       y = dinv_d*(sum H'[s] + H'[d]) + b  (dinv folded at both ends).
// ---------------------------------------------------------------------------

typedef __attribute__((ext_vector_type(8))) short bf16x8;
typedef __attribute__((ext_vector_type(4))) float f32x4;
typedef unsigned short u16;
typedef unsigned int u32;

static inline size_t alignup(size_t v, size_t a) { return (v + a - 1) & ~(a - 1); }

// pack top-16 bits of two f32 bit patterns into one u32 (lo half from b0)
__device__ __forceinline__ u32 pack_hi16(u32 b0, u32 b1) {
    return __builtin_amdgcn_perm(b1, b0, 0x07060302u);
}

// --- W pre-split into fragment-ordered bf16 hi/lo ----------------------------
// slot s = ((t*4+g)*F + c) holds W[t*32+g*8+j][c], j=0..7, as 8 bf16 (16 B).
template <int F>
__device__ __forceinline__ void splitW_one(const float* __restrict__ W,
                                           u16* __restrict__ Wh,
                                           u16* __restrict__ Wl, int s) {
    int c = s % F;
    int kb = (s / F) * 8;
    union { u32 u[4]; bf16x8 v; } hi, lo;
#pragma unroll
    for (int p = 0; p < 4; p++) {
        float x0 = W[(size_t)(kb + 2 * p) * F + c];
        float x1 = W[(size_t)(kb + 2 * p + 1) * F + c];
        u32 b0 = __float_as_uint(x0), b1 = __float_as_uint(x1);
        float l0 = x0 - __uint_as_float(b0 & 0xFFFF0000u);
        float l1 = x1 - __uint_as_float(b1 & 0xFFFF0000u);
        hi.u[p] = pack_hi16(b0, b1);
        lo.u[p] = pack_hi16(__float_as_uint(l0), __float_as_uint(l1));
    }
    *(bf16x8*)(Wh + (size_t)s * 8) = hi.v;
    *(bf16x8*)(Wl + (size_t)s * 8) = lo.v;
}

// --- init (zero deg + detect layout) fused with W splits ---------------------
__global__ void k_init_split(const int* __restrict__ ei, int* __restrict__ flag,
                             int* __restrict__ deg, int N, int nb,
                             const float* __restrict__ W1, u16* w1h, u16* w1l,
                             const float* __restrict__ W2, u16* w2h, u16* w2l,
                             const float* __restrict__ W3, u16* w3h, u16* w3l) {
    int b = blockIdx.x;
    if (b < nb) {
        int i = b * 256 + threadIdx.x;
        if (i < N) deg[i] = 0;
        if (b == 0 && threadIdx.x < 64) {
            int v = ei[2 * threadIdx.x + 1];          // high word if int64
            unsigned long long m = __ballot(v != 0);
            if (threadIdx.x == 0) *flag = (m == 0ull) ? 1 : 0;
        }
        return;
    }
    int s = (b - nb) * 256 + threadIdx.x;
    if (s < 8192) splitW_one<128>(W1, w1h, w1l, s);               // 512x128/8
    else if (s < 9216) splitW_one<64>(W2, w2h, w2l, s - 8192);    // 128x64/8
    else if (s < 9728) splitW_one<64>(W3, w3h, w3l, s - 9216);    // 64x64/8
}

__global__ void k_deg(const int* __restrict__ ei, int E,
                      const int* __restrict__ flag, int* __restrict__ deg) {
    int i = blockIdx.x * blockDim.x + threadIdx.x;
    if (i >= E) return;
    int is64 = *flag;
    int d = is64 ? ei[2 * (E + i)] : ei[E + i];
    atomicAdd(&deg[d], 1);
}

// --- scan stage 1: per-256-block exclusive scan of deg; also writes dinv ----
__global__ void k_scan1(const int* __restrict__ deg, int* __restrict__ offs,
                        int* __restrict__ bsums, float* __restrict__ dinv, int N) {
    __shared__ int s[256];
    int i = blockIdx.x * 256 + threadIdx.x;
    int v = (i < N) ? deg[i] : 0;
    if (i < N) dinv[i] = rsqrtf((float)v + 1.0f);
    s[threadIdx.x] = v;
    __syncthreads();
    for (int off = 1; off < 256; off <<= 1) {
        int t = (threadIdx.x >= off) ? s[threadIdx.x - off] : 0;
        __syncthreads();
        s[threadIdx.x] += t;
        __syncthreads();
    }
    if (i < N) offs[i] = s[threadIdx.x] - v;   // exclusive
    if (threadIdx.x == 255) bsums[blockIdx.x] = s[255];
}

// --- scan stages 2+3 fused: each block redundantly scans bsums (nb<=256) ----
__global__ void k_scan23(int* __restrict__ offs, const int* __restrict__ bsums,
                         int nb, int N, int E) {
    __shared__ int s[256];
    int tid = threadIdx.x;
    s[tid] = (tid < nb) ? bsums[tid] : 0;
    __syncthreads();
    for (int off = 1; off < 256; off <<= 1) {
        int t = (tid >= off) ? s[tid - off] : 0;
        __syncthreads();
        s[tid] += t;                 // inclusive scan
        __syncthreads();
    }
    int boff = (blockIdx.x > 0) ? s[blockIdx.x - 1] : 0;
    int i = blockIdx.x * 256 + tid;
    if (i < N) offs[i] += boff;
    if (i == 0) offs[N] = E;
}

// --- CSR fill via countdown on deg (no cnt array): slot = offs+old-1 --------
__global__ void k_fill(const int* __restrict__ ei, int E,
                       const int* __restrict__ flag,
                       const int* __restrict__ offs, int* __restrict__ deg,
                       int* __restrict__ csr) {
    int i = blockIdx.x * blockDim.x + threadIdx.x;
    if (i >= E) return;
    int is64 = *flag;
    int s = is64 ? ei[2 * i] : ei[i];
    int d = is64 ? ei[2 * (E + i)] : ei[E + i];
    int slot = offs[d] + atomicSub(&deg[d], 1) - 1;
    csr[slot] = s;
}

// --- MFMA GEMM: H'[N,F] = dinv_row * (X[N,K] @ W[K,F]), fp16 out -------------
// 256 thr = 4 waves (2 row-halves x 2 col-halves); block 64 rows x F cols.
// Wave tile 32 x F/2 (MF=2, NF=F/32). A K-tile [64][32] f32 double-buffered
// in LDS via global_load_lds; B direct global (L2-resident W splits).
template <int K, int F>
__global__ __launch_bounds__(256) void k_gemm_mfma(
        const float* __restrict__ X,
        const u16* __restrict__ Wh, const u16* __restrict__ Wl,
        const float* __restrict__ dinv, __half* __restrict__ Hh, int N) {
    constexpr int MF = 2;
    constexpr int NF = F / 32;         // 4 for F=128, 2 for F=64
    constexpr int NT = K / 32;         // K-steps
    __shared__ float4 smemA[2][512];   // 2 x 8 KB: [row][chunk] swizzled

    const int tid = threadIdx.x;
    const int lane = tid & 63;
    const int w = tid >> 6;            // 0..3
    const int wm = (w >> 1) * 32;      // row half: 0 or 32
    const int colbase = (w & 1) * (NF * 16);
    const int lg = lane >> 4, li = lane & 15;
    const int row0 = blockIdx.x * 64;

    // stage K-tile t into buffer b: lds chunk c_lin=(j*256+tid) holds
    // X[row0 + c_lin>>3][t*32 + ((c_lin&7)^(row&7))*4 ..+3]
    auto stage = [&](int b, int t) {
#pragma unroll
        for (int j = 0; j < 2; j++) {
            int c_lin = j * 256 + tid;
            int row = c_lin >> 3, c = c_lin & 7;
            int rg = row0 + row;
            if (rg >= N) rg = N - 1;
            int cs = c ^ (row & 7);
            const float* g = X + (size_t)rg * K + t * 32 + cs * 4;
            // dest: wave-uniform base + lane*16 (m104)
            char* l = (char*)&smemA[b][0] + j * 4096 + w * 1024;
            __builtin_amdgcn_global_load_lds(
                (const __attribute__((address_space(1))) void*)g,
                (__attribute__((address_space(3))) void*)l, 16, 0, 0);
        }
    };

    f32x4 acc[MF][NF];
#pragma unroll
    for (int m = 0; m < MF; m++)
#pragma unroll
        for (int n = 0; n < NF; n++) acc[m][n] = (f32x4){0.f, 0.f, 0.f, 0.f};

    stage(0, 0);
    __syncthreads();

    for (int t = 0; t < NT; t++) {
        const int b = t & 1;
        // B(t) loads FIRST (their vmcnt wait must not drain the stage DMA)
        bf16x8 bh[NF], bl[NF];
        size_t slot0 = (size_t)(t * 4 + lg) * F + colbase + li;
#pragma unroll
        for (int n = 0; n < NF; n++) {
            bh[n] = *(const bf16x8*)(Wh + (slot0 + n * 16) * 8);
            bl[n] = *(const bf16x8*)(Wl + (slot0 + n * 16) * 8);
        }
        __builtin_amdgcn_sched_barrier(0);   // keep B issued before stage
        if (t + 1 < NT) stage(b ^ 1, t + 1); // async DMA, drained at barrier
        // A(t) fragments from LDS (swizzled b128 reads) -> split -> MFMA
        const float4* lt = &smemA[b][0];
        bf16x8 ah[MF], al[MF];
#pragma unroll
        for (int m = 0; m < MF; m++) {
            int row = wm + m * 16 + li;
            int base = row * 8, sw = row & 7;
            float4 c0 = lt[base + ((2 * lg) ^ sw)];
            float4 c1 = lt[base + ((2 * lg + 1) ^ sw)];
            float xv[8] = {c0.x, c0.y, c0.z, c0.w, c1.x, c1.y, c1.z, c1.w};
            union { u32 u[4]; bf16x8 v; } hi, lo;
#pragma unroll
            for (int q = 0; q < 4; q++) {
                u32 b0 = __float_as_uint(xv[2 * q]);
                u32 b1 = __float_as_uint(xv[2 * q + 1]);
                float l0 = xv[2 * q]     - __uint_as_float(b0 & 0xFFFF0000u);
                float l1 = xv[2 * q + 1] - __uint_as_float(b1 & 0xFFFF0000u);
                hi.u[q] = pack_hi16(b0, b1);
                lo.u[q] = pack_hi16(__float_as_uint(l0), __float_as_uint(l1));
            }
            ah[m] = hi.v;
            al[m] = lo.v;
        }
        // 3-product accumulation: xh*wh + xh*wl + xl*wh
#pragma unroll
        for (int m = 0; m < MF; m++)
#pragma unroll
            for (int n = 0; n < NF; n++) {
                acc[m][n] = __builtin_amdgcn_mfma_f32_16x16x32_bf16(ah[m], bh[n], acc[m][n], 0, 0, 0);
                acc[m][n] = __builtin_amdgcn_mfma_f32_16x16x32_bf16(ah[m], bl[n], acc[m][n], 0, 0, 0);
                acc[m][n] = __builtin_amdgcn_mfma_f32_16x16x32_bf16(al[m], bh[n], acc[m][n], 0, 0, 0);
            }
        __syncthreads();   // drains stage(t+1) DMA + releases buf b for t+2
    }

    // C/D layout: col = lane&15, row = (lane>>4)*4 + reg (m89-verified)
    // Epilogue folds dinv[row] and converts to fp16.
#pragma unroll
    for (int m = 0; m < MF; m++) {
        int rb = row0 + wm + m * 16 + lg * 4;
#pragma unroll
        for (int r = 0; r < 4; r++) {
            int gr = rb + r;
            if (gr >= N) continue;
            float di = dinv[gr];
#pragma unroll
            for (int n = 0; n < NF; n++) {
                int col = colbase + n * 16 + li;
                Hh[(size_t)gr * F + col] = __float2half(acc[m][n][r] * di);
            }
        }
    }
}

// --- aggregation, F=128, fp16 H' in, f32 out ---------------------------------
// y = act(dinv_d * (sum_s H'[s] + H'[d]) + b); one wave per node; 4-edge unroll.
template <bool RELU>
__global__ __launch_bounds__(256) void k_agg128(const __half* __restrict__ Hh,
                                                const int* __restrict__ offs,
                                                const int* __restrict__ csr,
                                                const float* __restrict__ dinv,
                                                const float* __restrict__ bias,
                                                float* __restrict__ Y, int N) {
    int node = blockIdx.x * 4 + (threadIdx.x >> 6);
    int lane = threadIdx.x & 63;
    if (node >= N) return;
    const __half2* H2 = (const __half2*)Hh;   // row = 64 half2
    float ax = 0.f, ay = 0.f;
    int o0 = offs[node], o1 = offs[node + 1];
    int e = o0;
    for (; e + 4 <= o1; e += 4) {
        int s0 = csr[e], s1 = csr[e + 1], s2 = csr[e + 2], s3 = csr[e + 3];
        __half2 v0 = H2[(size_t)s0 * 64 + lane];
        __half2 v1 = H2[(size_t)s1 * 64 + lane];
        __half2 v2 = H2[(size_t)s2 * 64 + lane];
        __half2 v3 = H2[(size_t)s3 * 64 + lane];
        float2 f0 = __half22float2(v0), f1 = __half22float2(v1);
        float2 f2 = __half22float2(v2), f3 = __half22float2(v3);
        ax += (f0.x + f1.x) + (f2.x + f3.x);
        ay += (f0.y + f1.y) + (f2.y + f3.y);
    }
    for (; e < o1; ++e) {
        float2 f0 = __half22float2(H2[(size_t)csr[e] * 64 + lane]);
        ax += f0.x; ay += f0.y;
    }
    float2 fs = __half22float2(H2[(size_t)node * 64 + lane]);
    float di = dinv[node];
    float2 bv = ((const float2*)bias)[lane];
    float vx = di * (ax + fs.x) + bv.x;
    float vy = di * (ay + fs.y) + bv.y;
    if (RELU) { vx = vx > 0.f ? vx : 0.2f * vx; vy = vy > 0.f ? vy : 0.2f * vy; }
    ((float2*)Y)[(size_t)node * 64 + lane] = make_float2(vx, vy);
}

// --- aggregation, F=64, fp16 H' in, f32 out ----------------------------------
// Half-wave (32 lanes) per node: fp16 row = 128 B = 32 x half2. 8 nodes/block.
template <bool RELU>
__global__ __launch_bounds__(256) void k_agg64(const __half* __restrict__ Hh,
                                               const int* __restrict__ offs,
                                               const int* __restrict__ csr,
                                               const float* __restrict__ dinv,
                                               const float* __restrict__ bias,
                                               float* __restrict__ Y, int N) {
    int node = blockIdx.x * 8 + (threadIdx.x >> 5);
    int lane = threadIdx.x & 31;
    if (node >= N) return;
    const __half2* H2 = (const __half2*)Hh;   // row = 32 half2
    float ax = 0.f, ay = 0.f;
    int o0 = offs[node], o1 = offs[node + 1];
    int e = o0;
    for (; e + 4 <= o1; e += 4) {
        int s0 = csr[e], s1 = csr[e + 1], s2 = csr[e + 2], s3 = csr[e + 3];
        float2 f0 = __half22float2(H2[(size_t)s0 * 32 + lane]);
        float2 f1 = __half22float2(H2[(size_t)s1 * 32 + lane]);
        float2 f2 = __half22float2(H2[(size_t)s2 * 32 + lane]);
        float2 f3 = __half22float2(H2[(size_t)s3 * 32 + lane]);
        ax += (f0.x + f1.x) + (f2.x + f3.x);
        ay += (f0.y + f1.y) + (f2.y + f3.y);
    }
    for (; e < o1; ++e) {
        float2 f0 = __half22float2(H2[(size_t)csr[e] * 32 + lane]);
        ax += f0.x; ay += f0.y;
    }
    float2 fs = __half22float2(H2[(size_t)node * 32 + lane]);
    float di = dinv[node];
    float2 bv = ((const float2*)bias)[lane];
    float vx = di * (ax + fs.x) + bv.x;
    float vy = di * (ay + fs.y) + bv.y;
    if (RELU) { vx = vx > 0.f ? vx : 0.2f * vx; vy = vy > 0.f ? vy : 0.2f * vy; }
    ((float2*)Y)[(size_t)node * 32 + lane] = make_float2(vx, vy);
}

extern "C" void kernel_launch(void* const* d_in, const int* in_sizes, int n_in,
                              void* d_out, int out_size, void* d_ws, size_t ws_size,
                              hipStream_t stream) {
    const float* x  = (const float*)d_in[0];
    const int*   ei = (const int*)d_in[1];
    const float* W1 = (const float*)d_in[2];
    const float* b1 = (const float*)d_in[3];
    const float* W2 = (const float*)d_in[4];
    const float* b2 = (const float*)d_in[5];
    const float* W3 = (const float*)d_in[6];
    const float* b3 = (const float*)d_in[7];

    const int N = in_sizes[0] / 512;
    const int E = in_sizes[1] / 2;
    const int nb = (N + 255) / 256;

    char* w = (char*)d_ws;
    auto take = [&](size_t bytes) -> char* {
        char* p = w;
        w += alignup(bytes, 256);
        return p;
    };
    int*    flag  = (int*)take(256);
    int*    deg   = (int*)take((size_t)N * 4);
    int*    offs  = (int*)take((size_t)(N + 1) * 4);
    int*    bsums = (int*)take((size_t)nb * 4);
    int*    csr   = (int*)take((size_t)E * 4);
    float*  dinv  = (float*)take((size_t)N * 4);
    __half* bufA  = (__half*)take((size_t)N * 128 * 2);   // H' fp16
    float*  bufB  = (float*)take((size_t)N * 128 * 4);    // agg out f32
    u16*    w1h   = (u16*)take((size_t)512 * 128 * 2);
    u16*    w1l   = (u16*)take((size_t)512 * 128 * 2);
    u16*    w2h   = (u16*)take((size_t)128 * 64 * 2);
    u16*    w2l   = (u16*)take((size_t)128 * 64 * 2);
    u16*    w3h   = (u16*)take((size_t)64 * 64 * 2);
    u16*    w3l   = (u16*)take((size_t)64 * 64 * 2);

    const int TB = 256;
    // preprocessing (5 launches)
    k_init_split<<<nb + 38, TB, 0, stream>>>(ei, flag, deg, N, nb,
                                             W1, w1h, w1l, W2, w2h, w2l,
                                             W3, w3h, w3l);
    k_deg<<<(E + TB - 1) / TB, TB, 0, stream>>>(ei, E, flag, deg);
    k_scan1<<<nb, 256, 0, stream>>>(deg, offs, bsums, dinv, N);
    k_scan23<<<nb, 256, 0, stream>>>(offs, bsums, nb, N, E);
    k_fill<<<(E + TB - 1) / TB, TB, 0, stream>>>(ei, E, flag, offs, deg, csr);

    const int gemm_grid = (N + 63) / 64;
    // layer 1
    k_gemm_mfma<512, 128><<<gemm_grid, 256, 0, stream>>>(x, w1h, w1l, dinv, bufA, N);
    k_agg128<true><<<(N + 3) / 4, 256, 0, stream>>>(bufA, offs, csr, dinv, b1, bufB, N);
    // layer 2
    k_gemm_mfma<128, 64><<<gemm_grid, 256, 0, stream>>>(bufB, w2h, w2l, dinv, bufA, N);
    k_agg64<true><<<(N + 7) / 8, 256, 0, stream>>>(bufA, offs, csr, dinv, b2, bufB, N);
    // layer 3 (no relu), write straight to output
    k_gemm_mfma<64, 64><<<gemm_grid, 256, 0, stream>>>(bufB, w3h, w3l, dinv, bufA, N);
    k_agg64<false><<<(N + 7) / 8, 256, 0, stream>>>(bufA, offs, csr, dinv, b3,
                                                    (float*)d_out, N);
}

// Round 13
// 241.260 us; speedup vs baseline: 1.0177x; 1.0177x over previous
//
#include <hip/hip_runtime.h>
#include <hip/hip_fp16.h>

// ---------------------------------------------------------------------------
// GCN 3-layer forward on MI355X.  (r13: counted-vmcnt GEMM pipeline)
// init+splitW(fused) -> deg -> scan1(+dinv) -> scan23 -> fill(countdown)
//   -> [MFMA GEMM (bf16x3, LDS-staged A) -> AGG] x3          (11 launches)
// GEMM: r11 shape (64-row x F blocks, 2 waves = col halves, wave tile 64x64 /
//       64x32, MF=4) + T3/T4 counted pipeline: 3-buffer LDS A staged via
//       global_load_lds; per iter issue {stage(t+1) DMA, B(t+1) reg loads},
//       then asm s_waitcnt vmcnt(10|6) (waits ONLY for stage(t)+B(t) from
//       last iter) + RAW s_barrier -> compute. r12 post-mortem: __syncthreads
//       = vmcnt(0) drain killed the just-issued DMA every step (m97 stall);
//       counted wait keeps 10 loads in flight across the barrier (m201/T4).
// AGG:  per-dst gather of fp16 H' rows; F=128 wave/node, F=64 half-wave/node.
//       y = dinv_d*(sum H'[s] + H'[d]) + b  (dinv folded at both ends).
// ---------------------------------------------------------------------------

typedef __attribute__((ext_vector_type(8))) short bf16x8;
typedef __attribute__((ext_vector_type(4))) float f32x4;
typedef unsigned short u16;
typedef unsigned int u32;

static inline size_t alignup(size_t v, size_t a) { return (v + a - 1) & ~(a - 1); }

// pack top-16 bits of two f32 bit patterns into one u32 (lo half from b0)
__device__ __forceinline__ u32 pack_hi16(u32 b0, u32 b1) {
    return __builtin_amdgcn_perm(b1, b0, 0x07060302u);
}

// --- W pre-split into fragment-ordered bf16 hi/lo ----------------------------
// slot s = ((t*4+g)*F + c) holds W[t*32+g*8+j][c], j=0..7, as 8 bf16 (16 B).
template <int F>
__device__ __forceinline__ void splitW_one(const float* __restrict__ W,
                                           u16* __restrict__ Wh,
                                           u16* __restrict__ Wl, int s) {
    int c = s % F;
    int kb = (s / F) * 8;
    union { u32 u[4]; bf16x8 v; } hi, lo;
#pragma unroll
    for (int p = 0; p < 4; p++) {
        float x0 = W[(size_t)(kb + 2 * p) * F + c];
        float x1 = W[(size_t)(kb + 2 * p + 1) * F + c];
        u32 b0 = __float_as_uint(x0), b1 = __float_as_uint(x1);
        float l0 = x0 - __uint_as_float(b0 & 0xFFFF0000u);
        float l1 = x1 - __uint_as_float(b1 & 0xFFFF0000u);
        hi.u[p] = pack_hi16(b0, b1);
        lo.u[p] = pack_hi16(__float_as_uint(l0), __float_as_uint(l1));
    }
    *(bf16x8*)(Wh + (size_t)s * 8) = hi.v;
    *(bf16x8*)(Wl + (size_t)s * 8) = lo.v;
}

// --- init (zero deg + detect layout) fused with W splits ---------------------
__global__ void k_init_split(const int* __restrict__ ei, int* __restrict__ flag,
                             int* __restrict__ deg, int N, int nb,
                             const float* __restrict__ W1, u16* w1h, u16* w1l,
                             const float* __restrict__ W2, u16* w2h, u16* w2l,
                             const float* __restrict__ W3, u16* w3h, u16* w3l) {
    int b = blockIdx.x;
    if (b < nb) {
        int i = b * 256 + threadIdx.x;
        if (i < N) deg[i] = 0;
        if (b == 0 && threadIdx.x < 64) {
            int v = ei[2 * threadIdx.x + 1];          // high word if int64
            unsigned long long m = __ballot(v != 0);
            if (threadIdx.x == 0) *flag = (m == 0ull) ? 1 : 0;
        }
        return;
    }
    int s = (b - nb) * 256 + threadIdx.x;
    if (s < 8192) splitW_one<128>(W1, w1h, w1l, s);               // 512x128/8
    else if (s < 9216) splitW_one<64>(W2, w2h, w2l, s - 8192);    // 128x64/8
    else if (s < 9728) splitW_one<64>(W3, w3h, w3l, s - 9216);    // 64x64/8
}

__global__ void k_deg(const int* __restrict__ ei, int E,
                      const int* __restrict__ flag, int* __restrict__ deg) {
    int i = blockIdx.x * blockDim.x + threadIdx.x;
    if (i >= E) return;
    int is64 = *flag;
    int d = is64 ? ei[2 * (E + i)] : ei[E + i];
    atomicAdd(&deg[d], 1);
}

// --- scan stage 1: per-256-block exclusive scan of deg; also writes dinv ----
__global__ void k_scan1(const int* __restrict__ deg, int* __restrict__ offs,
                        int* __restrict__ bsums, float* __restrict__ dinv, int N) {
    __shared__ int s[256];
    int i = blockIdx.x * 256 + threadIdx.x;
    int v = (i < N) ? deg[i] : 0;
    if (i < N) dinv[i] = rsqrtf((float)v + 1.0f);
    s[threadIdx.x] = v;
    __syncthreads();
    for (int off = 1; off < 256; off <<= 1) {
        int t = (threadIdx.x >= off) ? s[threadIdx.x - off] : 0;
        __syncthreads();
        s[threadIdx.x] += t;
        __syncthreads();
    }
    if (i < N) offs[i] = s[threadIdx.x] - v;   // exclusive
    if (threadIdx.x == 255) bsums[blockIdx.x] = s[255];
}

// --- scan stages 2+3 fused: each block redundantly scans bsums (nb<=256) ----
__global__ void k_scan23(int* __restrict__ offs, const int* __restrict__ bsums,
                         int nb, int N, int E) {
    __shared__ int s[256];
    int tid = threadIdx.x;
    s[tid] = (tid < nb) ? bsums[tid] : 0;
    __syncthreads();
    for (int off = 1; off < 256; off <<= 1) {
        int t = (tid >= off) ? s[tid - off] : 0;
        __syncthreads();
        s[tid] += t;                 // inclusive scan
        __syncthreads();
    }
    int boff = (blockIdx.x > 0) ? s[blockIdx.x - 1] : 0;
    int i = blockIdx.x * 256 + tid;
    if (i < N) offs[i] += boff;
    if (i == 0) offs[N] = E;
}

// --- CSR fill via countdown on deg (no cnt array): slot = offs+old-1 --------
__global__ void k_fill(const int* __restrict__ ei, int E,
                       const int* __restrict__ flag,
                       const int* __restrict__ offs, int* __restrict__ deg,
                       int* __restrict__ csr) {
    int i = blockIdx.x * blockDim.x + threadIdx.x;
    if (i >= E) return;
    int is64 = *flag;
    int s = is64 ? ei[2 * i] : ei[i];
    int d = is64 ? ei[2 * (E + i)] : ei[E + i];
    int slot = offs[d] + atomicSub(&deg[d], 1) - 1;
    csr[slot] = s;
}

// --- MFMA GEMM: H'[N,F] = dinv_row * (X[N,K] @ W[K,F]), fp16 out -------------
// 128 thr = 2 waves (column halves); block 64 rows x F cols; grid 782.
// Wave tile 64 x F/2 (MF=4, NF=F/32). A K-tile [64][32] f32 in a 3-buffer
// LDS ring staged via global_load_lds; B reg-double-buffered; counted
// s_waitcnt vmcnt(N) + raw s_barrier keep next-step loads in flight.
template <int K, int F>
__global__ __launch_bounds__(128) void k_gemm_mfma(
        const float* __restrict__ X,
        const u16* __restrict__ Wh, const u16* __restrict__ Wl,
        const float* __restrict__ dinv, __half* __restrict__ Hh, int N) {
    constexpr int MF = 4;
    constexpr int NF = F / 32;         // 4 for F=128, 2 for F=64
    constexpr int NT = K / 32;         // K-steps
    __shared__ float4 smemA[3][512];   // 3 x 8 KB A-tile ring (skew-safe)

    const int tid = threadIdx.x;
    const int lane = tid & 63;
    const int w = tid >> 6;            // 0..1 column half
    const int colbase = w * (NF * 16);
    const int lg = lane >> 4, li = lane & 15;
    const int row0 = blockIdx.x * 64;

    // stage K-tile t into ring buffer: lds chunk c_lin=(j*128+tid) holds
    // X[row0 + c_lin>>3][t*32 + ((c_lin&7)^(row&7))*4 ..+3]   (2 DMA / lane)
    auto stage = [&](int buf, int t) {
#pragma unroll
        for (int j = 0; j < 4; j++) {
            int c_lin = j * 128 + tid;
            int row = c_lin >> 3, c = c_lin & 7;
            int rg = row0 + row;
            if (rg >= N) rg = N - 1;
            int cs = c ^ (row & 7);
            const float* g = X + (size_t)rg * K + t * 32 + cs * 4;
            // dest: wave-uniform base + lane*16 (m104)
            char* l = (char*)&smemA[buf][0] + j * 2048 + w * 1024;
            __builtin_amdgcn_global_load_lds(
                (const __attribute__((address_space(1))) void*)g,
                (__attribute__((address_space(3))) void*)l, 16, 0, 0);
        }
    };
    auto loadB = [&](bf16x8* bh, bf16x8* bl, int t) {
        size_t slot0 = (size_t)(t * 4 + lg) * F + colbase + li;
#pragma unroll
        for (int n = 0; n < NF; n++) {
            bh[n] = *(const bf16x8*)(Wh + (slot0 + n * 16) * 8);
            bl[n] = *(const bf16x8*)(Wl + (slot0 + n * 16) * 8);
        }
    };

    f32x4 acc[MF][NF];
#pragma unroll
    for (int m = 0; m < MF; m++)
#pragma unroll
        for (int n = 0; n < NF; n++) acc[m][n] = (f32x4){0.f, 0.f, 0.f, 0.f};

    // prologue: stage(0) + B(0) in flight (counted, not drained)
    bf16x8 bhc[NF], blc[NF], bhn[NF], bln[NF];
    stage(0, 0);
    loadB(bhc, blc, 0);

    for (int t = 0; t < NT; t++) {
        // issue next step's loads FIRST (they stay in flight across barrier)
        if (t + 1 < NT) {
            stage((t + 1) % 3, t + 1);
            loadB(bhn, bln, t + 1);
        }
        __builtin_amdgcn_sched_barrier(0);
        // wait ONLY for stage(t)+B(t) (issued last iter): leave the
        // 2 DMA + 2*NF B-loads just issued outstanding.
        if (t + 1 < NT) {
            if constexpr (NF == 4) asm volatile("s_waitcnt vmcnt(10)" ::: "memory");
            else                   asm volatile("s_waitcnt vmcnt(6)" ::: "memory");
        } else {
            asm volatile("s_waitcnt vmcnt(0)" ::: "memory");
        }
        __builtin_amdgcn_s_barrier();     // raw: no compiler vmcnt(0) drain
        __builtin_amdgcn_sched_barrier(0);
        // A(t) fragments from LDS ring (swizzled b128 reads) -> split -> MFMA
        const float4* lt = &smemA[t % 3][0];
        bf16x8 ah[MF], al[MF];
#pragma unroll
        for (int m = 0; m < MF; m++) {
            int row = m * 16 + li;
            int base = row * 8, sw = row & 7;
            float4 c0 = lt[base + ((2 * lg) ^ sw)];
            float4 c1 = lt[base + ((2 * lg + 1) ^ sw)];
            float xv[8] = {c0.x, c0.y, c0.z, c0.w, c1.x, c1.y, c1.z, c1.w};
            union { u32 u[4]; bf16x8 v; } hi, lo;
#pragma unroll
            for (int q = 0; q < 4; q++) {
                u32 b0 = __float_as_uint(xv[2 * q]);
                u32 b1 = __float_as_uint(xv[2 * q + 1]);
                float l0 = xv[2 * q]     - __uint_as_float(b0 & 0xFFFF0000u);
                float l1 = xv[2 * q + 1] - __uint_as_float(b1 & 0xFFFF0000u);
                hi.u[q] = pack_hi16(b0, b1);
                lo.u[q] = pack_hi16(__float_as_uint(l0), __float_as_uint(l1));
            }
            ah[m] = hi.v;
            al[m] = lo.v;
        }
        // 3-product accumulation: xh*wh + xh*wl + xl*wh
#pragma unroll
        for (int m = 0; m < MF; m++)
#pragma unroll
            for (int n = 0; n < NF; n++) {
                acc[m][n] = __builtin_amdgcn_mfma_f32_16x16x32_bf16(ah[m], bhc[n], acc[m][n], 0, 0, 0);
                acc[m][n] = __builtin_amdgcn_mfma_f32_16x16x32_bf16(ah[m], blc[n], acc[m][n], 0, 0, 0);
                acc[m][n] = __builtin_amdgcn_mfma_f32_16x16x32_bf16(al[m], bhc[n], acc[m][n], 0, 0, 0);
            }
        // rotate B double-buffer (unrolled copies rename registers)
        if (t + 1 < NT) {
#pragma unroll
            for (int n = 0; n < NF; n++) { bhc[n] = bhn[n]; blc[n] = bln[n]; }
        }
    }

    // C/D layout: col = lane&15, row = (lane>>4)*4 + reg (m89-verified)
    // Epilogue folds dinv[row] and converts to fp16.
#pragma unroll
    for (int m = 0; m < MF; m++) {
        int rb = row0 + m * 16 + lg * 4;
#pragma unroll
        for (int r = 0; r < 4; r++) {
            int gr = rb + r;
            if (gr >= N) continue;
            float di = dinv[gr];
#pragma unroll
            for (int n = 0; n < NF; n++) {
                int col = colbase + n * 16 + li;
                Hh[(size_t)gr * F + col] = __float2half(acc[m][n][r] * di);
            }
        }
    }
}

// --- aggregation, F=128, fp16 H' in, f32 out ---------------------------------
// y = act(dinv_d * (sum_s H'[s] + H'[d]) + b); one wave per node; 4-edge unroll.
template <bool RELU>
__global__ __launch_bounds__(256) void k_agg128(const __half* __restrict__ Hh,
                                                const int* __restrict__ offs,
                                                const int* __restrict__ csr,
                                                const float* __restrict__ dinv,
                                                const float* __restrict__ bias,
                                                float* __restrict__ Y, int N) {
    int node = blockIdx.x * 4 + (threadIdx.x >> 6);
    int lane = threadIdx.x & 63;
    if (node >= N) return;
    const __half2* H2 = (const __half2*)Hh;   // row = 64 half2
    float ax = 0.f, ay = 0.f;
    int o0 = offs[node], o1 = offs[node + 1];
    int e = o0;
    for (; e + 4 <= o1; e += 4) {
        int s0 = csr[e], s1 = csr[e + 1], s2 = csr[e + 2], s3 = csr[e + 3];
        __half2 v0 = H2[(size_t)s0 * 64 + lane];
        __half2 v1 = H2[(size_t)s1 * 64 + lane];
        __half2 v2 = H2[(size_t)s2 * 64 + lane];
        __half2 v3 = H2[(size_t)s3 * 64 + lane];
        float2 f0 = __half22float2(v0), f1 = __half22float2(v1);
        float2 f2 = __half22float2(v2), f3 = __half22float2(v3);
        ax += (f0.x + f1.x) + (f2.x + f3.x);
        ay += (f0.y + f1.y) + (f2.y + f3.y);
    }
    for (; e < o1; ++e) {
        float2 f0 = __half22float2(H2[(size_t)csr[e] * 64 + lane]);
        ax += f0.x; ay += f0.y;
    }
    float2 fs = __half22float2(H2[(size_t)node * 64 + lane]);
    float di = dinv[node];
    float2 bv = ((const float2*)bias)[lane];
    float vx = di * (ax + fs.x) + bv.x;
    float vy = di * (ay + fs.y) + bv.y;
    if (RELU) { vx = vx > 0.f ? vx : 0.2f * vx; vy = vy > 0.f ? vy : 0.2f * vy; }
    ((float2*)Y)[(size_t)node * 64 + lane] = make_float2(vx, vy);
}

// --- aggregation, F=64, fp16 H' in, f32 out ----------------------------------
// Half-wave (32 lanes) per node: fp16 row = 128 B = 32 x half2. 8 nodes/block.
template <bool RELU>
__global__ __launch_bounds__(256) void k_agg64(const __half* __restrict__ Hh,
                                               const int* __restrict__ offs,
                                               const int* __restrict__ csr,
                                               const float* __restrict__ dinv,
                                               const float* __restrict__ bias,
                                               float* __restrict__ Y, int N) {
    int node = blockIdx.x * 8 + (threadIdx.x >> 5);
    int lane = threadIdx.x & 31;
    if (node >= N) return;
    const __half2* H2 = (const __half2*)Hh;   // row = 32 half2
    float ax = 0.f, ay = 0.f;
    int o0 = offs[node], o1 = offs[node + 1];
    int e = o0;
    for (; e + 4 <= o1; e += 4) {
        int s0 = csr[e], s1 = csr[e + 1], s2 = csr[e + 2], s3 = csr[e + 3];
        float2 f0 = __half22float2(H2[(size_t)s0 * 32 + lane]);
        float2 f1 = __half22float2(H2[(size_t)s1 * 32 + lane]);
        float2 f2 = __half22float2(H2[(size_t)s2 * 32 + lane]);
        float2 f3 = __half22float2(H2[(size_t)s3 * 32 + lane]);
        ax += (f0.x + f1.x) + (f2.x + f3.x);
        ay += (f0.y + f1.y) + (f2.y + f3.y);
    }
    for (; e < o1; ++e) {
        float2 f0 = __half22float2(H2[(size_t)csr[e] * 32 + lane]);
        ax += f0.x; ay += f0.y;
    }
    float2 fs = __half22float2(H2[(size_t)node * 32 + lane]);
    float di = dinv[node];
    float2 bv = ((const float2*)bias)[lane];
    float vx = di * (ax + fs.x) + bv.x;
    float vy = di * (ay + fs.y) + bv.y;
    if (RELU) { vx = vx > 0.f ? vx : 0.2f * vx; vy = vy > 0.f ? vy : 0.2f * vy; }
    ((float2*)Y)[(size_t)node * 32 + lane] = make_float2(vx, vy);
}

extern "C" void kernel_launch(void* const* d_in, const int* in_sizes, int n_in,
                              void* d_out, int out_size, void* d_ws, size_t ws_size,
                              hipStream_t stream) {
    const float* x  = (const float*)d_in[0];
    const int*   ei = (const int*)d_in[1];
    const float* W1 = (const float*)d_in[2];
    const float* b1 = (const float*)d_in[3];
    const float* W2 = (const float*)d_in[4];
    const float* b2 = (const float*)d_in[5];
    const float* W3 = (const float*)d_in[6];
    const float* b3 = (const float*)d_in[7];

    const int N = in_sizes[0] / 512;
    const int E = in_sizes[1] / 2;
    const int nb = (N + 255) / 256;

    char* w = (char*)d_ws;
    auto take = [&](size_t bytes) -> char* {
        char* p = w;
        w += alignup(bytes, 256);
        return p;
    };
    int*    flag  = (int*)take(256);
    int*    deg   = (int*)take((size_t)N * 4);
    int*    offs  = (int*)take((size_t)(N + 1) * 4);
    int*    bsums = (int*)take((size_t)nb * 4);
    int*    csr   = (int*)take((size_t)E * 4);
    float*  dinv  = (float*)take((size_t)N * 4);
    __half* bufA  = (__half*)take((size_t)N * 128 * 2);   // H' fp16
    float*  bufB  = (float*)take((size_t)N * 128 * 4);    // agg out f32
    u16*    w1h   = (u16*)take((size_t)512 * 128 * 2);
    u16*    w1l   = (u16*)take((size_t)512 * 128 * 2);
    u16*    w2h   = (u16*)take((size_t)128 * 64 * 2);
    u16*    w2l   = (u16*)take((size_t)128 * 64 * 2);
    u16*    w3h   = (u16*)take((size_t)64 * 64 * 2);
    u16*    w3l   = (u16*)take((size_t)64 * 64 * 2);

    const int TB = 256;
    // preprocessing (5 launches)
    k_init_split<<<nb + 38, TB, 0, stream>>>(ei, flag, deg, N, nb,
                                             W1, w1h, w1l, W2, w2h, w2l,
                                             W3, w3h, w3l);
    k_deg<<<(E + TB - 1) / TB, TB, 0, stream>>>(ei, E, flag, deg);
    k_scan1<<<nb, 256, 0, stream>>>(deg, offs, bsums, dinv, N);
    k_scan23<<<nb, 256, 0, stream>>>(offs, bsums, nb, N, E);
    k_fill<<<(E + TB - 1) / TB, TB, 0, stream>>>(ei, E, flag, offs, deg, csr);

    const int gemm_grid = (N + 63) / 64;
    // layer 1
    k_gemm_mfma<512, 128><<<gemm_grid, 128, 0, stream>>>(x, w1h, w1l, dinv, bufA, N);
    k_agg128<true><<<(N + 3) / 4, 256, 0, stream>>>(bufA, offs, csr, dinv, b1, bufB, N);
    // layer 2
    k_gemm_mfma<128, 64><<<gemm_grid, 128, 0, stream>>>(bufB, w2h, w2l, dinv, bufA, N);
    k_agg64<true><<<(N + 7) / 8, 256, 0, stream>>>(bufA, offs, csr, dinv, b2, bufB, N);
    // layer 3 (no relu), write straight to output
    k_gemm_mfma<64, 64><<<gemm_grid, 128, 0, stream>>>(bufB, w3h, w3l, dinv, bufA, N);
    k_agg64<false><<<(N + 7) / 8, 256, 0, stream>>>(bufA, offs, csr, dinv, b3,
                                                    (float*)d_out, N);
}

// Round 14
// 231.356 us; speedup vs baseline: 1.0613x; 1.0428x over previous
//
#include <hip/hip_runtime.h>
#include <hip/hip_fp16.h>

// ---------------------------------------------------------------------------
// GCN 3-layer forward on MI355X.  (r14: fp16 layers 2/3 + named kernels)
// init+splitW -> deg -> scan1(+dinv) -> scan23 -> fill -> per layer:
//   L1: k_gemm_bf16 (X f32, bf16x3 split, LDS-staged) -> k_agg128 (y1 fp16)
//   L2: k_gemm2 (A=y1 fp16 EXACT, W fp16-split, 2 MFMA prods) -> k_agg64y
//   L3: k_gemm3 (A=y2 fp16) -> k_agg64out (f32 d_out)
// r6-r13 lesson: gemm1 ~60us invariant under all schedule surgery (register
// prefetch, counted vmcnt, wave shapes) -> structural wall; this round cuts
// WORK on layers 2/3 instead (fp16 A needs no split; 2-product W split).
// ---------------------------------------------------------------------------

typedef __attribute__((ext_vector_type(8))) short bf16x8;
typedef __attribute__((ext_vector_type(8))) _Float16 f16x8;
typedef __attribute__((ext_vector_type(4))) float f32x4;
typedef unsigned short u16;
typedef unsigned int u32;

static inline size_t alignup(size_t v, size_t a) { return (v + a - 1) & ~(a - 1); }

__device__ __forceinline__ u32 pack_hi16(u32 b0, u32 b1) {
    return __builtin_amdgcn_perm(b1, b0, 0x07060302u);   // top16(b0)|top16(b1)
}

// --- W1 split: fragment-ordered bf16 hi/lo -----------------------------------
__device__ __forceinline__ void splitW_bf16(const float* __restrict__ W,
                                            u16* __restrict__ Wh,
                                            u16* __restrict__ Wl, int s, int F) {
    int c = s % F;
    int kb = (s / F) * 8;
    union { u32 u[4]; bf16x8 v; } hi, lo;
#pragma unroll
    for (int p = 0; p < 4; p++) {
        float x0 = W[(size_t)(kb + 2 * p) * F + c];
        float x1 = W[(size_t)(kb + 2 * p + 1) * F + c];
        u32 b0 = __float_as_uint(x0), b1 = __float_as_uint(x1);
        float l0 = x0 - __uint_as_float(b0 & 0xFFFF0000u);
        float l1 = x1 - __uint_as_float(b1 & 0xFFFF0000u);
        hi.u[p] = pack_hi16(b0, b1);
        lo.u[p] = pack_hi16(__float_as_uint(l0), __float_as_uint(l1));
    }
    *(bf16x8*)(Wh + (size_t)s * 8) = hi.v;
    *(bf16x8*)(Wl + (size_t)s * 8) = lo.v;
}

// --- W2/W3 split: fragment-ordered fp16 hi/lo (22-bit effective) -------------
__device__ __forceinline__ void splitW_f16(const float* __restrict__ W,
                                           u16* __restrict__ Wh,
                                           u16* __restrict__ Wl, int s, int F) {
    int c = s % F;
    int kb = (s / F) * 8;
    union { u16 u[8]; bf16x8 v; } hi, lo;
#pragma unroll
    for (int p = 0; p < 8; p++) {
        float xv = W[(size_t)(kb + p) * F + c];
        __half h = __float2half(xv);
        __half l = __float2half(xv - __half2float(h));
        hi.u[p] = __half_as_ushort(h);
        lo.u[p] = __half_as_ushort(l);
    }
    *(bf16x8*)(Wh + (size_t)s * 8) = hi.v;
    *(bf16x8*)(Wl + (size_t)s * 8) = lo.v;
}

// --- init (zero deg + detect layout) fused with W splits ---------------------
__global__ void k_init_split(const int* __restrict__ ei, int* __restrict__ flag,
                             int* __restrict__ deg, int N, int nb,
                             const float* __restrict__ W1, u16* w1h, u16* w1l,
                             const float* __restrict__ W2, u16* w2h, u16* w2l,
                             const float* __restrict__ W3, u16* w3h, u16* w3l) {
    int b = blockIdx.x;
    if (b < nb) {
        int i = b * 256 + threadIdx.x;
        if (i < N) deg[i] = 0;
        if (b == 0 && threadIdx.x < 64) {
            int v = ei[2 * threadIdx.x + 1];          // high word if int64
            unsigned long long m = __ballot(v != 0);
            if (threadIdx.x == 0) *flag = (m == 0ull) ? 1 : 0;
        }
        return;
    }
    int s = (b - nb) * 256 + threadIdx.x;
    if (s < 8192) splitW_bf16(W1, w1h, w1l, s, 128);              // 512x128/8
    else if (s < 9216) splitW_f16(W2, w2h, w2l, s - 8192, 64);    // 128x64/8
    else if (s < 9728) splitW_f16(W3, w3h, w3l, s - 9216, 64);    // 64x64/8
}

__global__ void k_deg(const int* __restrict__ ei, int E,
                      const int* __restrict__ flag, int* __restrict__ deg) {
    int i = blockIdx.x * blockDim.x + threadIdx.x;
    if (i >= E) return;
    int is64 = *flag;
    int d = is64 ? ei[2 * (E + i)] : ei[E + i];
    atomicAdd(&deg[d], 1);
}

__global__ void k_scan1(const int* __restrict__ deg, int* __restrict__ offs,
                        int* __restrict__ bsums, float* __restrict__ dinv, int N) {
    __shared__ int s[256];
    int i = blockIdx.x * 256 + threadIdx.x;
    int v = (i < N) ? deg[i] : 0;
    if (i < N) dinv[i] = rsqrtf((float)v + 1.0f);
    s[threadIdx.x] = v;
    __syncthreads();
    for (int off = 1; off < 256; off <<= 1) {
        int t = (threadIdx.x >= off) ? s[threadIdx.x - off] : 0;
        __syncthreads();
        s[threadIdx.x] += t;
        __syncthreads();
    }
    if (i < N) offs[i] = s[threadIdx.x] - v;   // exclusive
    if (threadIdx.x == 255) bsums[blockIdx.x] = s[255];
}

__global__ void k_scan23(int* __restrict__ offs, const int* __restrict__ bsums,
                         int nb, int N, int E) {
    __shared__ int s[256];
    int tid = threadIdx.x;
    s[tid] = (tid < nb) ? bsums[tid] : 0;
    __syncthreads();
    for (int off = 1; off < 256; off <<= 1) {
        int t = (tid >= off) ? s[tid - off] : 0;
        __syncthreads();
        s[tid] += t;                 // inclusive scan
        __syncthreads();
    }
    int boff = (blockIdx.x > 0) ? s[blockIdx.x - 1] : 0;
    int i = blockIdx.x * 256 + tid;
    if (i < N) offs[i] += boff;
    if (i == 0) offs[N] = E;
}

__global__ void k_fill(const int* __restrict__ ei, int E,
                       const int* __restrict__ flag,
                       const int* __restrict__ offs, int* __restrict__ deg,
                       int* __restrict__ csr) {
    int i = blockIdx.x * blockDim.x + threadIdx.x;
    if (i >= E) return;
    int is64 = *flag;
    int s = is64 ? ei[2 * i] : ei[i];
    int d = is64 ? ei[2 * (E + i)] : ei[E + i];
    int slot = offs[d] + atomicSub(&deg[d], 1) - 1;
    csr[slot] = s;
}

// --- L1 GEMM: H'[N,128] = dinv * (X[N,512] @ W1), bf16x3, fp16 out -----------
// r11 structure: 128 thr = 2 waves (col halves), wave tile 64x64 (MF=4,NF=4),
// A K-tile [64][32] f32 dbuf LDS via global_load_lds (src swizzle c^=(row&7)).
__global__ __launch_bounds__(128) void k_gemm_bf16(
        const float* __restrict__ X,
        const u16* __restrict__ Wh, const u16* __restrict__ Wl,
        const float* __restrict__ dinv, __half* __restrict__ Hh, int N) {
    constexpr int K = 512, F = 128, MF = 4, NF = 4, NT = K / 32;
    __shared__ float4 smemA[2][512];   // 2 x 8 KB

    const int tid = threadIdx.x;
    const int lane = tid & 63;
    const int w = tid >> 6;
    const int colbase = w * (NF * 16);
    const int lg = lane >> 4, li = lane & 15;
    const int row0 = blockIdx.x * 64;

    auto stage = [&](int b, int t) {
#pragma unroll
        for (int j = 0; j < 4; j++) {
            int c_lin = j * 128 + tid;
            int row = c_lin >> 3, c = c_lin & 7;
            int rg = row0 + row;
            if (rg >= N) rg = N - 1;
            int cs = c ^ (row & 7);
            const float* g = X + (size_t)rg * K + t * 32 + cs * 4;
            char* l = (char*)&smemA[b][0] + j * 2048 + w * 1024;
            __builtin_amdgcn_global_load_lds(
                (const __attribute__((address_space(1))) void*)g,
                (__attribute__((address_space(3))) void*)l, 16, 0, 0);
        }
    };

    f32x4 acc[MF][NF];
#pragma unroll
    for (int m = 0; m < MF; m++)
#pragma unroll
        for (int n = 0; n < NF; n++) acc[m][n] = (f32x4){0.f, 0.f, 0.f, 0.f};

    stage(0, 0);
    __syncthreads();

    for (int t = 0; t < NT; t++) {
        const int b = t & 1;
        bf16x8 bh[NF], bl[NF];
        size_t slot0 = (size_t)(t * 4 + lg) * F + colbase + li;
#pragma unroll
        for (int n = 0; n < NF; n++) {
            bh[n] = *(const bf16x8*)(Wh + (slot0 + n * 16) * 8);
            bl[n] = *(const bf16x8*)(Wl + (slot0 + n * 16) * 8);
        }
        __builtin_amdgcn_sched_barrier(0);
        if (t + 1 < NT) stage(b ^ 1, t + 1);
        const float4* lt = &smemA[b][0];
        bf16x8 ah[MF], al[MF];
#pragma unroll
        for (int m = 0; m < MF; m++) {
            int row = m * 16 + li;
            int base = row * 8, sw = row & 7;
            float4 c0 = lt[base + ((2 * lg) ^ sw)];
            float4 c1 = lt[base + ((2 * lg + 1) ^ sw)];
            float xv[8] = {c0.x, c0.y, c0.z, c0.w, c1.x, c1.y, c1.z, c1.w};
            union { u32 u[4]; bf16x8 v; } hi, lo;
#pragma unroll
            for (int q = 0; q < 4; q++) {
                u32 b0 = __float_as_uint(xv[2 * q]);
                u32 b1 = __float_as_uint(xv[2 * q + 1]);
                float l0 = xv[2 * q]     - __uint_as_float(b0 & 0xFFFF0000u);
                float l1 = xv[2 * q + 1] - __uint_as_float(b1 & 0xFFFF0000u);
                hi.u[q] = pack_hi16(b0, b1);
                lo.u[q] = pack_hi16(__float_as_uint(l0), __float_as_uint(l1));
            }
            ah[m] = hi.v;
            al[m] = lo.v;
        }
#pragma unroll
        for (int m = 0; m < MF; m++)
#pragma unroll
            for (int n = 0; n < NF; n++) {
                acc[m][n] = __builtin_amdgcn_mfma_f32_16x16x32_bf16(ah[m], bh[n], acc[m][n], 0, 0, 0);
                acc[m][n] = __builtin_amdgcn_mfma_f32_16x16x32_bf16(ah[m], bl[n], acc[m][n], 0, 0, 0);
                acc[m][n] = __builtin_amdgcn_mfma_f32_16x16x32_bf16(al[m], bh[n], acc[m][n], 0, 0, 0);
            }
        __syncthreads();
    }

#pragma unroll
    for (int m = 0; m < MF; m++) {
        int rb = row0 + m * 16 + lg * 4;
#pragma unroll
        for (int r = 0; r < 4; r++) {
            int gr = rb + r;
            if (gr >= N) continue;
            float di = dinv[gr];
#pragma unroll
            for (int n = 0; n < NF; n++) {
                int col = colbase + n * 16 + li;
                Hh[(size_t)gr * F + col] = __float2half(acc[m][n][r] * di);
            }
        }
    }
}

// --- L2/L3 GEMM body: H'[N,64] = dinv * (Y[N,K] @ W), Y fp16 EXACT -----------
// A needs no split (already fp16); W pre-split fp16 hi/lo -> 2 MFMA products.
// 128 thr = 2 waves (col halves), wave tile 64x32 (MF=4, NF=2).
// A K-tile [64 rows][32 k] fp16 (4 KB) dbuf LDS, src chunk-swizzle c^=(row&3).
template <int K>
__device__ __forceinline__ void gemm_f16_body(
        const __half* __restrict__ Y,
        const u16* __restrict__ Wh, const u16* __restrict__ Wl,
        const float* __restrict__ dinv, __half* __restrict__ Hh, int N) {
    constexpr int F = 64, MF = 4, NF = 2, NT = K / 32;
    __shared__ float4 smemA[2][256];   // 2 x 4 KB

    const int tid = threadIdx.x;
    const int lane = tid & 63;
    const int w = tid >> 6;
    const int colbase = w * (NF * 16);
    const int lg = lane >> 4, li = lane & 15;
    const int row0 = blockIdx.x * 64;

    auto stage = [&](int b, int t) {
#pragma unroll
        for (int j = 0; j < 2; j++) {
            int c_lin = j * 128 + tid;          // 0..255
            int row = c_lin >> 2, c = c_lin & 3;
            int rg = row0 + row;
            if (rg >= N) rg = N - 1;
            int cs = c ^ (row & 3);
            const __half* g = Y + (size_t)rg * K + t * 32 + cs * 8;  // 16 B
            char* l = (char*)&smemA[b][0] + j * 2048 + w * 1024;
            __builtin_amdgcn_global_load_lds(
                (const __attribute__((address_space(1))) void*)g,
                (__attribute__((address_space(3))) void*)l, 16, 0, 0);
        }
    };

    f32x4 acc[MF][NF];
#pragma unroll
    for (int m = 0; m < MF; m++)
#pragma unroll
        for (int n = 0; n < NF; n++) acc[m][n] = (f32x4){0.f, 0.f, 0.f, 0.f};

    stage(0, 0);
    __syncthreads();

    for (int t = 0; t < NT; t++) {
        const int b = t & 1;
        f16x8 bh[NF], bl[NF];
        size_t slot0 = (size_t)(t * 4 + lg) * F + colbase + li;
#pragma unroll
        for (int n = 0; n < NF; n++) {
            bh[n] = *(const f16x8*)(Wh + (slot0 + n * 16) * 8);
            bl[n] = *(const f16x8*)(Wl + (slot0 + n * 16) * 8);
        }
        __builtin_amdgcn_sched_barrier(0);
        if (t + 1 < NT) stage(b ^ 1, t + 1);
        const float4* lt = &smemA[b][0];
        f16x8 a[MF];
#pragma unroll
        for (int m = 0; m < MF; m++) {
            int row = m * 16 + li;
            union { float4 f; f16x8 h; } u;
            u.f = lt[row * 4 + (lg ^ (row & 3))];
            a[m] = u.h;
        }
#pragma unroll
        for (int m = 0; m < MF; m++)
#pragma unroll
            for (int n = 0; n < NF; n++) {
                acc[m][n] = __builtin_amdgcn_mfma_f32_16x16x32_f16(a[m], bh[n], acc[m][n], 0, 0, 0);
                acc[m][n] = __builtin_amdgcn_mfma_f32_16x16x32_f16(a[m], bl[n], acc[m][n], 0, 0, 0);
            }
        __syncthreads();
    }

#pragma unroll
    for (int m = 0; m < MF; m++) {
        int rb = row0 + m * 16 + lg * 4;
#pragma unroll
        for (int r = 0; r < 4; r++) {
            int gr = rb + r;
            if (gr >= N) continue;
            float di = dinv[gr];
#pragma unroll
            for (int n = 0; n < NF; n++) {
                int col = colbase + n * 16 + li;
                Hh[(size_t)gr * F + col] = __float2half(acc[m][n][r] * di);
            }
        }
    }
}

__global__ __launch_bounds__(128) void k_gemm2(
        const __half* __restrict__ Y, const u16* __restrict__ Wh,
        const u16* __restrict__ Wl, const float* __restrict__ dinv,
        __half* __restrict__ Hh, int N) {
    gemm_f16_body<128>(Y, Wh, Wl, dinv, Hh, N);
}
__global__ __launch_bounds__(128) void k_gemm3(
        const __half* __restrict__ Y, const u16* __restrict__ Wh,
        const u16* __restrict__ Wl, const float* __restrict__ dinv,
        __half* __restrict__ Hh, int N) {
    gemm_f16_body<64>(Y, Wh, Wl, dinv, Hh, N);
}

// --- agg, F=128, fp16 H' in, fp16 y out (leaky-relu) --------------------------
__global__ __launch_bounds__(256) void k_agg128(const __half* __restrict__ Hh,
                                                const int* __restrict__ offs,
                                                const int* __restrict__ csr,
                                                const float* __restrict__ dinv,
                                                const float* __restrict__ bias,
                                                __half* __restrict__ Y, int N) {
    int node = blockIdx.x * 4 + (threadIdx.x >> 6);
    int lane = threadIdx.x & 63;
    if (node >= N) return;
    const __half2* H2 = (const __half2*)Hh;   // row = 64 half2
    float ax = 0.f, ay = 0.f;
    int o0 = offs[node], o1 = offs[node + 1];
    int e = o0;
    for (; e + 4 <= o1; e += 4) {
        int s0 = csr[e], s1 = csr[e + 1], s2 = csr[e + 2], s3 = csr[e + 3];
        float2 f0 = __half22float2(H2[(size_t)s0 * 64 + lane]);
        float2 f1 = __half22float2(H2[(size_t)s1 * 64 + lane]);
        float2 f2 = __half22float2(H2[(size_t)s2 * 64 + lane]);
        float2 f3 = __half22float2(H2[(size_t)s3 * 64 + lane]);
        ax += (f0.x + f1.x) + (f2.x + f3.x);
        ay += (f0.y + f1.y) + (f2.y + f3.y);
    }
    for (; e < o1; ++e) {
        float2 f0 = __half22float2(H2[(size_t)csr[e] * 64 + lane]);
        ax += f0.x; ay += f0.y;
    }
    float2 fs = __half22float2(H2[(size_t)node * 64 + lane]);
    float di = dinv[node];
    float2 bv = ((const float2*)bias)[lane];
    float vx = di * (ax + fs.x) + bv.x;
    float vy = di * (ay + fs.y) + bv.y;
    vx = vx > 0.f ? vx : 0.2f * vx;
    vy = vy > 0.f ? vy : 0.2f * vy;
    ((__half2*)Y)[(size_t)node * 64 + lane] = __floats2half2_rn(vx, vy);
}

// --- agg, F=64, fp16 H' in — shared body, fp16-y or f32-out variants ---------
template <bool RELU, bool OUT16>
__device__ __forceinline__ void agg64_body(const __half* __restrict__ Hh,
                                           const int* __restrict__ offs,
                                           const int* __restrict__ csr,
                                           const float* __restrict__ dinv,
                                           const float* __restrict__ bias,
                                           void* __restrict__ Y, int N) {
    int node = blockIdx.x * 8 + (threadIdx.x >> 5);
    int lane = threadIdx.x & 31;
    if (node >= N) return;
    const __half2* H2 = (const __half2*)Hh;   // row = 32 half2
    float ax = 0.f, ay = 0.f;
    int o0 = offs[node], o1 = offs[node + 1];
    int e = o0;
    for (; e + 4 <= o1; e += 4) {
        int s0 = csr[e], s1 = csr[e + 1], s2 = csr[e + 2], s3 = csr[e + 3];
        float2 f0 = __half22float2(H2[(size_t)s0 * 32 + lane]);
        float2 f1 = __half22float2(H2[(size_t)s1 * 32 + lane]);
        float2 f2 = __half22float2(H2[(size_t)s2 * 32 + lane]);
        float2 f3 = __half22float2(H2[(size_t)s3 * 32 + lane]);
        ax += (f0.x + f1.x) + (f2.x + f3.x);
        ay += (f0.y + f1.y) + (f2.y + f3.y);
    }
    for (; e < o1; ++e) {
        float2 f0 = __half22float2(H2[(size_t)csr[e] * 32 + lane]);
        ax += f0.x; ay += f0.y;
    }
    float2 fs = __half22float2(H2[(size_t)node * 32 + lane]);
    float di = dinv[node];
    float2 bv = ((const float2*)bias)[lane];
    float vx = di * (ax + fs.x) + bv.x;
    float vy = di * (ay + fs.y) + bv.y;
    if (RELU) { vx = vx > 0.f ? vx : 0.2f * vx; vy = vy > 0.f ? vy : 0.2f * vy; }
    if (OUT16)
        ((__half2*)Y)[(size_t)node * 32 + lane] = __floats2half2_rn(vx, vy);
    else
        ((float2*)Y)[(size_t)node * 32 + lane] = make_float2(vx, vy);
}

__global__ __launch_bounds__(256) void k_agg64y(const __half* Hh, const int* offs,
                                                const int* csr, const float* dinv,
                                                const float* bias, __half* Y, int N) {
    agg64_body<true, true>(Hh, offs, csr, dinv, bias, Y, N);
}
__global__ __launch_bounds__(256) void k_agg64out(const __half* Hh, const int* offs,
                                                  const int* csr, const float* dinv,
                                                  const float* bias, float* Y, int N) {
    agg64_body<false, false>(Hh, offs, csr, dinv, bias, Y, N);
}

extern "C" void kernel_launch(void* const* d_in, const int* in_sizes, int n_in,
                              void* d_out, int out_size, void* d_ws, size_t ws_size,
                              hipStream_t stream) {
    const float* x  = (const float*)d_in[0];
    const int*   ei = (const int*)d_in[1];
    const float* W1 = (const float*)d_in[2];
    const float* b1 = (const float*)d_in[3];
    const float* W2 = (const float*)d_in[4];
    const float* b2 = (const float*)d_in[5];
    const float* W3 = (const float*)d_in[6];
    const float* b3 = (const float*)d_in[7];

    const int N = in_sizes[0] / 512;
    const int E = in_sizes[1] / 2;
    const int nb = (N + 255) / 256;

    char* w = (char*)d_ws;
    auto take = [&](size_t bytes) -> char* {
        char* p = w;
        w += alignup(bytes, 256);
        return p;
    };
    int*    flag  = (int*)take(256);
    int*    deg   = (int*)take((size_t)N * 4);
    int*    offs  = (int*)take((size_t)(N + 1) * 4);
    int*    bsums = (int*)take((size_t)nb * 4);
    int*    csr   = (int*)take((size_t)E * 4);
    float*  dinv  = (float*)take((size_t)N * 4);
    __half* bufA  = (__half*)take((size_t)N * 128 * 2);   // H' fp16
    __half* bufY  = (__half*)take((size_t)N * 128 * 2);   // y fp16
    u16*    w1h   = (u16*)take((size_t)512 * 128 * 2);
    u16*    w1l   = (u16*)take((size_t)512 * 128 * 2);
    u16*    w2h   = (u16*)take((size_t)128 * 64 * 2);
    u16*    w2l   = (u16*)take((size_t)128 * 64 * 2);
    u16*    w3h   = (u16*)take((size_t)64 * 64 * 2);
    u16*    w3l   = (u16*)take((size_t)64 * 64 * 2);

    const int TB = 256;
    // preprocessing (5 launches)
    k_init_split<<<nb + 38, TB, 0, stream>>>(ei, flag, deg, N, nb,
                                             W1, w1h, w1l, W2, w2h, w2l,
                                             W3, w3h, w3l);
    k_deg<<<(E + TB - 1) / TB, TB, 0, stream>>>(ei, E, flag, deg);
    k_scan1<<<nb, 256, 0, stream>>>(deg, offs, bsums, dinv, N);
    k_scan23<<<nb, 256, 0, stream>>>(offs, bsums, nb, N, E);
    k_fill<<<(E + TB - 1) / TB, TB, 0, stream>>>(ei, E, flag, offs, deg, csr);

    const int gemm_grid = (N + 63) / 64;
    // layer 1
    k_gemm_bf16<<<gemm_grid, 128, 0, stream>>>(x, w1h, w1l, dinv, bufA, N);
    k_agg128<<<(N + 3) / 4, 256, 0, stream>>>(bufA, offs, csr, dinv, b1, bufY, N);
    // layer 2
    k_gemm2<<<gemm_grid, 128, 0, stream>>>(bufY, w2h, w2l, dinv, bufA, N);
    k_agg64y<<<(N + 7) / 8, 256, 0, stream>>>(bufA, offs, csr, dinv, b2, bufY, N);
    // layer 3
    k_gemm3<<<gemm_grid, 128, 0, stream>>>(bufY, w3h, w3l, dinv, bufA, N);
    k_agg64out<<<(N + 7) / 8, 256, 0, stream>>>(bufA, offs, csr, dinv, b3,
                                                (float*)d_out, N);
}